// Round 14
// baseline (68.463 us; speedup 1.0000x reference)
//
#include <hip/hip_runtime.h>
#include <math.h>

#define NBINS 15
#define NCLS  100
#define NHALF 50               // float2 slots per row
#define NSEG  (NBINS * NCLS)   // 1500
#define TROWS 64               // rows per tile
#define TF4   (TROWS * NCLS / 4)   // 1600 float4 per tile
#define NTHR  1024
#define NBLK  512

// DPP-based wave64 sum on the VALU pipe (no DS ops). ctrl must be literal.
template <int CTRL>
__device__ __forceinline__ float dpp_add_f32(float x) {
    int y = __builtin_amdgcn_update_dpp(0, __float_as_int(x), CTRL, 0xf, 0xf, true);
    return x + __int_as_float(y);
}
__device__ __forceinline__ float wave_sum64(float x) {
    x = dpp_add_f32<0x111>(x);   // row_shr:1
    x = dpp_add_f32<0x112>(x);   // row_shr:2
    x = dpp_add_f32<0x114>(x);   // row_shr:4
    x = dpp_add_f32<0x118>(x);   // row_shr:8
    x = dpp_add_f32<0x142>(x);   // row_bcast:15
    x = dpp_add_f32<0x143>(x);   // row_bcast:31 -> lane 63 = total
    return __int_as_float(__builtin_amdgcn_readlane(__float_as_int(x), 63));
}

#define GAS __attribute__((address_space(1)))
#define LAS __attribute__((address_space(3)))

// Double-buffered async tile staging (dense 64-lane float4 global_load_lds,
// the probe_lin pattern) + round-6 per-row compute from LDS.
// One barrier per tile: its compiler-emitted vmcnt(0) drain IS the stage wait,
// placed AFTER compute so compute hides under the stage (T3 minimum 2-phase).
__global__ __launch_bounds__(NTHR, 8)
void ece_hist(const float* __restrict__ logits,
              const int* __restrict__ labels,
              int N,
              double* __restrict__ g_conf,
              unsigned int* __restrict__ g_acc)
{
    __shared__ __align__(16) float4 s_buf[2][TF4];   // 2 x 25.6 KB
    __shared__ float        s_conf[NSEG];
    __shared__ unsigned int s_acc[NSEG];

    const int tid = threadIdx.x;
    for (int i = tid; i < NSEG; i += NTHR) { s_conf[i] = 0.0f; s_acc[i] = 0u; }

    const int  lane = tid & 63;
    const int  w    = tid >> 6;              // wave 0..15 -> rows w*4..w*4+3
    const bool act  = lane < NHALF;

    float        conf0_a = 0.0f, conf0_b = 0.0f;
    unsigned int acc0_a  = 0u,   acc0_b  = 0u;

    const float4* g4     = reinterpret_cast<const float4*>(logits);
    const int     ntiles = (N + TROWS - 1) / TROWS;
    const int     t0     = blockIdx.x;

    // Prologue: stage this block's first tile into buffer 0.
    if (t0 < ntiles) {
        const int    rows = min(TROWS, N - t0 * TROWS);
        const int    nf4  = rows * (NCLS / 4);
        const size_t gb   = (size_t)t0 * TF4;
        for (int i = tid; i < nf4; i += NTHR)
            __builtin_amdgcn_global_load_lds((const GAS void*)(g4 + gb + i),
                                             (LAS void*)&s_buf[0][i], 16, 0, 0);
    }
    __syncthreads();   // drains stage; also orders histogram zeroing

    int cur = 0;
    for (int t = t0; t < ntiles; t += NBLK) {
        // Issue async stage of the NEXT tile into the other buffer.
        const int tn = t + NBLK;
        if (tn < ntiles) {
            const int    rowsn = min(TROWS, N - tn * TROWS);
            const int    nf4n  = rowsn * (NCLS / 4);
            const size_t gbn   = (size_t)tn * TF4;
            for (int i = tid; i < nf4n; i += NTHR)
                __builtin_amdgcn_global_load_lds((const GAS void*)(g4 + gbn + i),
                                                 (LAS void*)&s_buf[cur ^ 1][i], 16, 0, 0);
        }

        // Compute current tile from LDS (round-6 body).
        const int start = t * TROWS;
        const int rows  = min(TROWS, N - start);
        const int r0    = w * 4;
        if (r0 < rows) {
            const bool    full = (r0 + 4 <= rows);
            const float2* s2   = reinterpret_cast<const float2*>(&s_buf[cur][0]);
            float e0[4], e1[4], s[4];
            int   lbl[4];

            if (full) {
                #pragma unroll
                for (int r = 0; r < 4; ++r) {
                    float2 v = act ? s2[(r0 + r) * NHALF + lane] : make_float2(0.f, 0.f);
                    e0[r] = v.x; e1[r] = v.y;
                }
                const int4 lb = *reinterpret_cast<const int4*>(labels + start + r0);
                lbl[0] = lb.x; lbl[1] = lb.y; lbl[2] = lb.z; lbl[3] = lb.w;
            } else {
                #pragma unroll
                for (int r = 0; r < 4; ++r) {
                    int rr = min(r0 + r, rows - 1);
                    float2 v = act ? s2[rr * NHALF + lane] : make_float2(0.f, 0.f);
                    e0[r] = v.x; e1[r] = v.y;
                    lbl[r] = labels[start + rr];
                }
            }

            #pragma unroll
            for (int r = 0; r < 4; ++r) {
                e0[r] = act ? __expf(e0[r]) : 0.0f;
                e1[r] = act ? __expf(e1[r]) : 0.0f;
            }
            #pragma unroll
            for (int r = 0; r < 4; ++r) s[r] = wave_sum64(e0[r] + e1[r]);

            #pragma unroll
            for (int r = 0; r < 4; ++r) {
                if (!full && r0 + r >= rows) break;
                const float inv    = __builtin_amdgcn_rcpf(s[r]);      // ~1 ulp
                const float thresh = s[r] * (1.0f / (float)NBINS);     // e > thresh <=> bin >= 1
                const int   lb     = lbl[r];
                const bool  mine   = (lane == (lb >> 1));
                const int   lbbit  = lb & 1;

                {
                    float p0 = e0[r] * inv;
                    if (e0[r] > thresh) {                  // rare: bin >= 1
                        int b0 = min((int)ceilf(p0 * (float)NBINS) - 1, NBINS - 1);
                        atomicAdd(&s_conf[(2 * lane) * NBINS + b0], p0);
                        if (mine && lbbit == 0) atomicAdd(&s_acc[(2 * lane) * NBINS + b0], 1u);
                    } else {                               // hot: bin 0, register
                        conf0_a += p0;
                        if (mine && lbbit == 0) ++acc0_a;
                    }
                }
                {
                    float p1 = e1[r] * inv;
                    if (e1[r] > thresh) {
                        int b1 = min((int)ceilf(p1 * (float)NBINS) - 1, NBINS - 1);
                        atomicAdd(&s_conf[(2 * lane + 1) * NBINS + b1], p1);
                        if (mine && lbbit == 1) atomicAdd(&s_acc[(2 * lane + 1) * NBINS + b1], 1u);
                    } else {
                        conf0_b += p1;
                        if (mine && lbbit == 1) ++acc0_b;
                    }
                }
            }
        }

        __syncthreads();   // waits for next-tile stage (vmcnt drain) + readers done
        cur ^= 1;
    }

    // Flush per-lane register accumulators into the LDS histogram (once).
    if (act) {
        atomicAdd(&s_conf[(2 * lane) * NBINS], conf0_a);
        if (acc0_a) atomicAdd(&s_acc[(2 * lane) * NBINS], acc0_a);
        atomicAdd(&s_conf[(2 * lane + 1) * NBINS], conf0_b);
        if (acc0_b) atomicAdd(&s_acc[(2 * lane + 1) * NBINS], acc0_b);
    }

    __syncthreads();
    // Flush block partials; rotate start so concurrent blocks hit different
    // global addresses.
    const int rot = (blockIdx.x * 61) % NSEG;
    for (int i = tid; i < NSEG; i += NTHR) {
        int j = i + rot; if (j >= NSEG) j -= NSEG;
        float        c = s_conf[j];
        unsigned int a = s_acc[j];
        if (c != 0.0f) atomicAdd(&g_conf[j], (double)c);
        if (a)         atomicAdd(&g_acc[j], a);
    }
}

// result = sum_j |conf_sum[j] - acc_sum[j]| / (N*C)
__global__ void ece_final(const double* __restrict__ g_conf,
                          const unsigned int* __restrict__ g_acc,
                          float* __restrict__ out, double inv_nc)
{
    __shared__ double sh[16];
    double t = 0.0;
    for (int i = threadIdx.x; i < NSEG; i += blockDim.x)
        t += fabs(g_conf[i] - (double)g_acc[i]);
    #pragma unroll
    for (int off = 32; off; off >>= 1) t += __shfl_xor(t, off);
    const int lane = threadIdx.x & 63, w = threadIdx.x >> 6;
    if (lane == 0) sh[w] = t;
    __syncthreads();
    if (threadIdx.x == 0) {
        double tot = 0.0;
        const int nw = (int)(blockDim.x >> 6);
        for (int i = 0; i < nw; ++i) tot += sh[i];
        out[0] = (float)(tot * inv_nc);
    }
}

extern "C" void kernel_launch(void* const* d_in, const int* in_sizes, int n_in,
                              void* d_out, int out_size, void* d_ws, size_t ws_size,
                              hipStream_t stream)
{
    const float* logits = (const float*)d_in[0];
    const int*   labels = (const int*)d_in[1];
    const int N = in_sizes[1];   // labels count = row count

    double*       g_conf = (double*)d_ws;
    unsigned int* g_acc  = (unsigned int*)(g_conf + NSEG);

    (void)hipMemsetAsync(d_ws, 0, NSEG * sizeof(double) + NSEG * sizeof(unsigned int), stream);

    ece_hist<<<NBLK, NTHR, 0, stream>>>(logits, labels, N, g_conf, g_acc);

    const double inv_nc = 1.0 / ((double)N * (double)NCLS);
    ece_final<<<1, 256, 0, stream>>>(g_conf, g_acc, (float*)d_out, inv_nc);
}